// Round 6
// baseline (268.312 us; speedup 1.0000x reference)
//
#include <hip/hip_runtime.h>
#include <hip/hip_bf16.h>

#define B_ 4
#define U_ 16
#define L_ 128
#define H_ 768
#define M_ 256
#define HID_ 150

typedef _Float16 half8 __attribute__((ext_vector_type(8)));
typedef _Float16 half4t __attribute__((ext_vector_type(4)));
typedef float floatx4 __attribute__((ext_vector_type(4)));
typedef float floatx16 __attribute__((ext_vector_type(16)));

// ---------------------------------------------------------------------------
// Kernel 0: prepack weights (COALESCED-READ version; same output formats as R5,
// formulas spot-verified: W1cs sample (k=17,n=37)->3113, W1abs (11,21)->683).
// W1cs frag layout: lane l of (kc,t1) holds A[m=t1*32+(l&31)][k=kc*16+(l>>5)*8+j]
// W2s same with 10 kc. W1abs: 16x16 B-frags for hihj.
// bw: float2[160] = (b2[n], W3[n]).
// ---------------------------------------------------------------------------
__global__ __launch_bounds__(256) void prep_kernel(
    const float* __restrict__ W1, const float* __restrict__ W2,
    const float* __restrict__ b2, const float* __restrict__ W3,
    _Float16* __restrict__ W1cs, _Float16* __restrict__ W2s,
    _Float16* __restrict__ W1abs, float2* __restrict__ bw)
{
    int idx = blockIdx.x * 256 + threadIdx.x;
    if (blockIdx.x == 0 && threadIdx.x < 160) {
        int n = threadIdx.x;
        bw[n] = (n < HID_) ? make_float2(b2[n], W3[n]) : make_float2(0.f, 0.f);
    }
    if (idx < 122880) {   // W1cs: idx = k*160 + n (n-inner -> coalesced read)
        int k = idx / 160, n = idx - k * 160;
        float v = (n < HID_) ? W1[(size_t)(2 * H_ + k) * HID_ + n] : 0.f;
        W1cs[(k >> 4) * 2560 + (n >> 5) * 512 +
             (((n & 31) | (((k >> 3) & 1) << 5)) << 3) + (k & 7)] = (_Float16)v;
        return;
    }
    idx -= 122880;
    if (idx < 25600) {    // W2s: idx = k*160 + n
        int k = idx / 160, n = idx - k * 160;
        float v = (k < HID_ && n < HID_) ? W2[(size_t)k * HID_ + n] : 0.f;
        W2s[(k >> 4) * 2560 + (n >> 5) * 512 +
            (((n & 31) | (((k >> 3) & 1) << 5)) << 3) + (k & 7)] = (_Float16)v;
        return;
    }
    idx -= 25600;
    if (idx < 245760) {   // W1abs: idx = k*320 + n
        int k = idx / 320, n = idx - k * 320;
        float v = 0.f;
        if (n < HID_) v = W1[(size_t)k * HID_ + n];
        else if (n >= 160 && n < 160 + HID_) v = W1[(size_t)(H_ + k) * HID_ + (n - 160)];
        W1abs[(k >> 5) * 10240 + (n >> 4) * 512 +
              (((n & 15) | (((k >> 3) & 3) << 4)) << 3) + (k & 7)] = (_Float16)v;
    }
}

// ---------------------------------------------------------------------------
// Kernel 1: masked mean-pool -> f16. Full-GPU grid (256 blocks x 4 rows).
// 64 threads per row, 12 cols each (3 x float4 loads, 3 x half4 writes).
// ---------------------------------------------------------------------------
__global__ __launch_bounds__(256) void pool_kernel(
    const float* __restrict__ hidden, const int* __restrict__ sutt,
    const int* __restrict__ sstart, const int* __restrict__ send,
    _Float16* __restrict__ pooledh)
{
    const int bm = blockIdx.x * 4 + (threadIdx.x >> 6);
    const int lane = threadIdx.x & 63;
    const int b  = bm >> 8;
    const int u  = sutt[bm];
    const int st = sstart[bm];
    const int en = send[bm];
    const float inv = 1.0f / (float)(en - st);
    const float* src = hidden + ((size_t)(b * U_ + u) * L_) * H_ + lane * 12;
    float4 s[3];
    #pragma unroll
    for (int q = 0; q < 3; ++q) s[q] = make_float4(0.f, 0.f, 0.f, 0.f);
    for (int l = st; l < en; ++l) {
        const float* p = src + (size_t)l * H_;
        #pragma unroll
        for (int q = 0; q < 3; ++q) {
            float4 v = *(const float4*)(p + q * 4);
            s[q].x += v.x; s[q].y += v.y; s[q].z += v.z; s[q].w += v.w;
        }
    }
    _Float16* gp = pooledh + (size_t)bm * H_ + lane * 12;
    #pragma unroll
    for (int q = 0; q < 3; ++q) {
        half4t hv;
        hv[0] = (_Float16)(s[q].x * inv); hv[1] = (_Float16)(s[q].y * inv);
        hv[2] = (_Float16)(s[q].z * inv); hv[3] = (_Float16)(s[q].w * inv);
        *(half4t*)(gp + q * 4) = hv;
    }
}

// ---------------------------------------------------------------------------
// Kernel 2: hi/hj projection. 64 blocks x 16 rows, 16x16x32 MFMA vs W1abs.
// hiF[row][160] (b1 folded), hjT[160][1024] transposed.
// ---------------------------------------------------------------------------
__global__ __launch_bounds__(256) void hihj_kernel(
    const _Float16* __restrict__ pooledh, const float* __restrict__ b1,
    const _Float16* __restrict__ W1abs,
    float* __restrict__ hiF, float* __restrict__ hjT)
{
    __shared__ __align__(16) _Float16 spool[16 * 776];
    const int blk = blockIdx.x;
    const int tid = threadIdx.x;
    for (int e = tid; e < 16 * 96; e += 256) {
        int r = e / 96, c = e - r * 96;
        *(half8*)&spool[r * 776 + c * 8] =
            *(const half8*)&pooledh[(size_t)(blk * 16 + r) * H_ + c * 8];
    }
    __syncthreads();

    const int w = tid >> 6, lane = tid & 63;
    const int g = lane >> 4, l15 = lane & 15;
    floatx4 acc[5];
    #pragma unroll
    for (int u5 = 0; u5 < 5; ++u5) acc[u5] = (floatx4){0.f, 0.f, 0.f, 0.f};
    const _Float16* aB = &spool[l15 * 776 + g * 8];
    for (int kc = 0; kc < 24; ++kc) {
        half8 av = *(const half8*)(aB + kc * 32);
        #pragma unroll
        for (int u5 = 0; u5 < 5; ++u5) {
            const int u = w * 5 + u5;
            half8 bv = *(const half8*)(W1abs + (size_t)((kc * 20 + u) * 64 + lane) * 8);
            acc[u5] = __builtin_amdgcn_mfma_f32_16x16x32_f16(av, bv, acc[u5], 0, 0, 0);
        }
    }
    const int row0 = blk * 16 + g * 4;
    #pragma unroll
    for (int u5 = 0; u5 < 5; ++u5) {
        const int n = (w * 5 + u5) * 16 + l15;
        if (n < HID_) {
            float b1v = b1[n];
            #pragma unroll
            for (int r = 0; r < 4; ++r)
                hiF[(size_t)(row0 + r) * 160 + n] = acc[u5][r] + b1v;
        } else if (n >= 160 && n < 160 + HID_) {
            *(float4*)&hjT[(size_t)(n - 160) * 1024 + row0] =
                make_float4(acc[u5][0], acc[u5][1], acc[u5][2], acc[u5][3]);
        }
    }
}

// ---------------------------------------------------------------------------
// Kernel 3: fused pair MLP. Block = 4 waves (256 thr), all waves share jt.
// Wave w owns i-pair p = 16*jt + 4*g + w -> 2 tiles (i0, i0+1) x 32 j.
// Stage1 weights: LDS double-buffer (shared by 4 waves; 4x L2 traffic cut),
// 1 barrier/chunk. h1: wave-private LDS region, per-tile sequential (no
// barrier; same-wave lgkmcnt ordering). LDS 62.5 KB -> 2 blocks/CU.
// launch_bounds(256,2): cap 256 regs/wave -> 2 waves/SIMD (acc 160 + ~80 V).
// C/D 32x32: col=lane&31, row=(reg&3)+8*(reg>>2)+4*(lane>>5).  [R4-verified]
// ---------------------------------------------------------------------------
__global__ __launch_bounds__(256, 2) void pair_mlp_kernel(
    const _Float16* __restrict__ pooledh,
    const float* __restrict__ hiF, const float* __restrict__ hjT,
    const _Float16* __restrict__ W1cs, const _Float16* __restrict__ W2s,
    const float2* __restrict__ bw, const float* __restrict__ b3,
    float* __restrict__ logits)
{
    __shared__ __align__(16) _Float16 sW[2][5120];   // 20 KB dbuf
    __shared__ __align__(16) _Float16 h1L[4][5440];  // 42.5 KB, per-wave 32x170

    const int b = blockIdx.y;
    int t = blockIdx.x;                  // 0..143
    int jt = 0;
    while (t >= 32 - 4 * jt) { t -= 32 - 4 * jt; ++jt; }
    const int tid = threadIdx.x;
    const int w = tid >> 6, lane = tid & 63;
    const int p = 16 * jt + 4 * t + w;   // i-pair
    const int i0 = 2 * p, j0 = 32 * jt;
    const int bm = b * M_;
    const int c31 = lane & 31, hw = lane >> 5;

    const _Float16* pjp  = pooledh + (size_t)(bm + j0 + c31) * H_ + (hw << 3);
    const _Float16* pip0 = pooledh + (size_t)(bm + i0) * H_ + (hw << 3);
    const _Float16* pip1 = pooledh + (size_t)(bm + i0 + 1) * H_ + (hw << 3);

    floatx16 acc1[2][5];
    #pragma unroll
    for (int tt = 0; tt < 2; ++tt)
        #pragma unroll
        for (int t1 = 0; t1 < 5; ++t1)
            #pragma unroll
            for (int e = 0; e < 16; ++e) acc1[tt][t1][e] = 0.f;

    // ---- prologue: stage W1c chunk 0 ----
    half8 s0 = *(const half8*)(W1cs + (size_t)tid * 8);
    half8 s1 = *(const half8*)(W1cs + (size_t)(tid + 256) * 8);
    half8 s2;
    if (tid < 128) s2 = *(const half8*)(W1cs + (size_t)(tid + 512) * 8);
    *(half8*)&sW[0][tid * 8] = s0;
    *(half8*)&sW[0][(tid + 256) * 8] = s1;
    if (tid < 128) *(half8*)&sW[0][(tid + 512) * 8] = s2;
    __syncthreads();

    // ---- stage 1: K=768, 24 chunks of 32 ----
    for (int kc = 0; kc < 24; ++kc) {
        const int pp = kc & 1;
        if (kc < 23) {
            const _Float16* g = W1cs + (size_t)(kc + 1) * 5120;
            s0 = *(const half8*)(g + (size_t)tid * 8);
            s1 = *(const half8*)(g + (size_t)(tid + 256) * 8);
            if (tid < 128) s2 = *(const half8*)(g + (size_t)(tid + 512) * 8);
        }
        half8 pj0  = *(const half8*)(pjp + kc * 32);
        half8 pj1  = *(const half8*)(pjp + kc * 32 + 16);
        half8 pi00 = *(const half8*)(pip0 + kc * 32);
        half8 pi01 = *(const half8*)(pip0 + kc * 32 + 16);
        half8 pi10 = *(const half8*)(pip1 + kc * 32);
        half8 pi11 = *(const half8*)(pip1 + kc * 32 + 16);
        #pragma unroll
        for (int h = 0; h < 2; ++h) {
            half8 pj = h ? pj1 : pj0;
            half8 a0 = (h ? pi01 : pi00) * pj;
            half8 a1 = (h ? pi11 : pi10) * pj;
            const _Float16* base = &sW[pp][h * 2560 + lane * 8];
            #pragma unroll
            for (int t1 = 0; t1 < 5; ++t1) {
                half8 wf = *(const half8*)(base + t1 * 512);
                acc1[0][t1] = __builtin_amdgcn_mfma_f32_32x32x16_f16(
                    wf, a0, acc1[0][t1], 0, 0, 0);
                acc1[1][t1] = __builtin_amdgcn_mfma_f32_32x32x16_f16(
                    wf, a1, acc1[1][t1], 0, 0, 0);
            }
        }
        if (kc < 23) {
            *(half8*)&sW[1 - pp][tid * 8] = s0;
            *(half8*)&sW[1 - pp][(tid + 256) * 8] = s1;
            if (tid < 128) *(half8*)&sW[1 - pp][(tid + 512) * 8] = s2;
            __syncthreads();
        }
    }

    // ---- per tile: epilogue1 -> private LDS -> stage2 -> stage3 ----
    const float b3v = b3[0];
    _Float16* h1w = h1L[w];
    #pragma unroll
    for (int tt = 0; tt < 2; ++tt) {
        #pragma unroll
        for (int t1 = 0; t1 < 5; ++t1) {
            #pragma unroll
            for (int qd = 0; qd < 4; ++qd) {
                const int n1 = t1 * 32 + 8 * qd + 4 * hw;
                float hj0 = hjT[(size_t)(n1 + 0) * 1024 + bm + j0 + c31];
                float hj1 = hjT[(size_t)(n1 + 1) * 1024 + bm + j0 + c31];
                float hj2 = hjT[(size_t)(n1 + 2) * 1024 + bm + j0 + c31];
                float hj3 = hjT[(size_t)(n1 + 3) * 1024 + bm + j0 + c31];
                float4 hiv = *(const float4*)&hiF[(size_t)(bm + i0 + tt) * 160 + n1];
                half4t hv;
                hv[0] = (_Float16)fmaxf(acc1[tt][t1][4 * qd + 0] + hiv.x + hj0, 0.f);
                hv[1] = (_Float16)fmaxf(acc1[tt][t1][4 * qd + 1] + hiv.y + hj1, 0.f);
                hv[2] = (_Float16)fmaxf(acc1[tt][t1][4 * qd + 2] + hiv.z + hj2, 0.f);
                hv[3] = (_Float16)fmaxf(acc1[tt][t1][4 * qd + 3] + hiv.w + hj3, 0.f);
                *(half4t*)&h1w[c31 * 170 + n1] = hv;
            }
        }
        // stage 2 (wave-private h1, no barrier needed)
        floatx16 acc2[5];
        #pragma unroll
        for (int t2 = 0; t2 < 5; ++t2)
            #pragma unroll
            for (int e = 0; e < 16; ++e) acc2[t2][e] = 0.f;
        for (int kc2 = 0; kc2 < 10; ++kc2) {
            half8 b2f = *(const half8*)&h1w[c31 * 170 + kc2 * 16 + hw * 8];
            const _Float16* wb = W2s + (size_t)(kc2 * 5) * 512 + lane * 8;
            #pragma unroll
            for (int t2 = 0; t2 < 5; ++t2) {
                half8 wf = *(const half8*)(wb + t2 * 512);
                acc2[t2] = __builtin_amdgcn_mfma_f32_32x32x16_f16(
                    wf, b2f, acc2[t2], 0, 0, 0);
            }
        }
        // stage 3
        float sown = 0.f;
        #pragma unroll
        for (int t2 = 0; t2 < 5; ++t2) {
            #pragma unroll
            for (int qd = 0; qd < 4; ++qd) {
                const int n2 = t2 * 32 + 8 * qd + 4 * hw;
                float4 bw01 = *(const float4*)&bw[n2];
                float4 bw23 = *(const float4*)&bw[n2 + 2];
                sown += fmaxf(acc2[t2][4 * qd + 0] + bw01.x, 0.f) * bw01.y;
                sown += fmaxf(acc2[t2][4 * qd + 1] + bw01.z, 0.f) * bw01.w;
                sown += fmaxf(acc2[t2][4 * qd + 2] + bw23.x, 0.f) * bw23.y;
                sown += fmaxf(acc2[t2][4 * qd + 3] + bw23.z, 0.f) * bw23.w;
            }
        }
        float s = sown + __shfl_xor(sown, 32);
        const int i = i0 + tt;
        const int j = j0 + c31;
        if (lane < 32 && j < i)
            logits[(size_t)(bm + i) * M_ + j] = s + b3v;
    }
}

// ---------------------------------------------------------------------------
// Kernel 4: per-row softmax over j<=i, clipped label-mass NLL, atomic sum.
// ---------------------------------------------------------------------------
__global__ __launch_bounds__(256) void loss_kernel(
    const float* __restrict__ logits, const float* __restrict__ labels,
    float* __restrict__ out)
{
    const int bm = blockIdx.x;
    const int i  = bm & (M_ - 1);
    const int j  = threadIdx.x;
    __shared__ float red[4];
    __shared__ float bcast;

    float val = (j < i) ? logits[(size_t)bm * M_ + j]
                        : ((j == i) ? 0.0f : -1e30f);

    float m = val;
    #pragma unroll
    for (int off = 32; off >= 1; off >>= 1) m = fmaxf(m, __shfl_down(m, off, 64));
    const int wave = j >> 6, lane = j & 63;
    if (lane == 0) red[wave] = m;
    __syncthreads();
    if (j == 0) bcast = fmaxf(fmaxf(red[0], red[1]), fmaxf(red[2], red[3]));
    __syncthreads();
    const float mm = bcast;

    float e = (j <= i) ? expf(val - mm) : 0.0f;
    float s = e;
    #pragma unroll
    for (int off = 32; off >= 1; off >>= 1) s += __shfl_down(s, off, 64);
    __syncthreads();
    if (lane == 0) red[wave] = s;
    __syncthreads();
    if (j == 0) bcast = red[0] + red[1] + red[2] + red[3];
    __syncthreads();
    const float ssum = bcast;

    float prob = (j <= i) ? (e / ssum) : -1000.0f;
    float lab = labels[(size_t)bm * M_ + j];
    float tv = prob * lab;
    tv = fminf(fmaxf(tv, 1e-8f), 1.0f - 1e-8f);
    float rs = tv;
    #pragma unroll
    for (int off = 32; off >= 1; off >>= 1) rs += __shfl_down(rs, off, 64);
    __syncthreads();
    if (lane == 0) red[wave] = rs;
    __syncthreads();
    if (j == 0) atomicAdd(out, -logf(red[0] + red[1] + red[2] + red[3]));
}

// ---------------------------------------------------------------------------
extern "C" void kernel_launch(void* const* d_in, const int* in_sizes, int n_in,
                              void* d_out, int out_size, void* d_ws, size_t ws_size,
                              hipStream_t stream)
{
    const float* hidden = (const float*)d_in[0];
    const int*   sutt   = (const int*)d_in[1];
    const int*   sstart = (const int*)d_in[2];
    const int*   send   = (const int*)d_in[3];
    const float* labels = (const float*)d_in[4];
    const float* W1     = (const float*)d_in[5];
    const float* b1     = (const float*)d_in[6];
    const float* W2     = (const float*)d_in[7];
    const float* b2     = (const float*)d_in[8];
    const float* W3     = (const float*)d_in[9];
    const float* b3     = (const float*)d_in[10];

    float* ws = (float*)d_ws;
    float*    hiF     = ws;                          // [1024][160] = 163840
    float*    hjT     = ws + 163840;                 // [160][1024] = 163840
    float*    logits  = ws + 327680;                 // 262144
    float2*   bw      = (float2*)(ws + 589824);      // 160 float2
    _Float16* pooledh = (_Float16*)(ws + 590144);    // 786432 f16
    _Float16* W1cs    = (_Float16*)(ws + 983360);    // 122880 f16
    _Float16* W2s     = (_Float16*)(ws + 1106240);   // 25600 f16
    _Float16* W1abs   = (_Float16*)(ws + 1119040);   // 245760 f16
    float* out = (float*)d_out;

    hipMemsetAsync(d_out, 0, sizeof(float), stream);

    prep_kernel<<<dim3(1540), 256, 0, stream>>>(W1, W2, b2, W3,
                                                W1cs, W2s, W1abs, bw);
    pool_kernel<<<dim3(256), 256, 0, stream>>>(hidden, sutt, sstart, send, pooledh);
    hihj_kernel<<<dim3(64), 256, 0, stream>>>(pooledh, b1, W1abs, hiF, hjT);
    pair_mlp_kernel<<<dim3(144, B_), 256, 0, stream>>>(pooledh, hiF, hjT,
                                                       W1cs, W2s, bw, b3, logits);
    loss_kernel<<<dim3(B_ * M_), 256, 0, stream>>>(logits, labels, out);
}

// Round 7
// 209.724 us; speedup vs baseline: 1.2794x; 1.2794x over previous
//
#include <hip/hip_runtime.h>
#include <hip/hip_bf16.h>

#define B_ 4
#define U_ 16
#define L_ 128
#define H_ 768
#define M_ 256
#define HID_ 150

typedef _Float16 half8 __attribute__((ext_vector_type(8)));
typedef _Float16 half4t __attribute__((ext_vector_type(4)));
typedef float floatx4 __attribute__((ext_vector_type(4)));
typedef float floatx16 __attribute__((ext_vector_type(16)));

// ---------------------------------------------------------------------------
// Kernel 0: prepack weights (coalesced reads; formats HW-verified in R6).
// W1cs frag: lane l of (kc16,t1) holds A[m=t1*32+(l&31)][k=kc16*8? see map]
//   store: (k>>4)*2560 + (n>>5)*512 + (((n&31)|(((k>>3)&1)<<5))<<3) + (k&7)
// W2s same with K=160. W1abs: 16x16 B-frags for hihj.
// bw: float2[160] = (b2[n], W3[n]).
// ---------------------------------------------------------------------------
__global__ __launch_bounds__(256) void prep_kernel(
    const float* __restrict__ W1, const float* __restrict__ W2,
    const float* __restrict__ b2, const float* __restrict__ W3,
    _Float16* __restrict__ W1cs, _Float16* __restrict__ W2s,
    _Float16* __restrict__ W1abs, float2* __restrict__ bw)
{
    int idx = blockIdx.x * 256 + threadIdx.x;
    if (blockIdx.x == 0 && threadIdx.x < 160) {
        int n = threadIdx.x;
        bw[n] = (n < HID_) ? make_float2(b2[n], W3[n]) : make_float2(0.f, 0.f);
    }
    if (idx < 122880) {   // W1cs: idx = k*160 + n (n-inner -> coalesced read)
        int k = idx / 160, n = idx - k * 160;
        float v = (n < HID_) ? W1[(size_t)(2 * H_ + k) * HID_ + n] : 0.f;
        W1cs[(k >> 4) * 2560 + (n >> 5) * 512 +
             (((n & 31) | (((k >> 3) & 1) << 5)) << 3) + (k & 7)] = (_Float16)v;
        return;
    }
    idx -= 122880;
    if (idx < 25600) {    // W2s: idx = k*160 + n
        int k = idx / 160, n = idx - k * 160;
        float v = (k < HID_ && n < HID_) ? W2[(size_t)k * HID_ + n] : 0.f;
        W2s[(k >> 4) * 2560 + (n >> 5) * 512 +
            (((n & 31) | (((k >> 3) & 1) << 5)) << 3) + (k & 7)] = (_Float16)v;
        return;
    }
    idx -= 25600;
    if (idx < 245760) {   // W1abs: idx = k*320 + n
        int k = idx / 320, n = idx - k * 320;
        float v = 0.f;
        if (n < HID_) v = W1[(size_t)k * HID_ + n];
        else if (n >= 160 && n < 160 + HID_) v = W1[(size_t)(H_ + k) * HID_ + (n - 160)];
        W1abs[(k >> 5) * 10240 + (n >> 4) * 512 +
              (((n & 15) | (((k >> 3) & 3) << 4)) << 3) + (k & 7)] = (_Float16)v;
    }
}

// ---------------------------------------------------------------------------
// Kernel 1: masked mean-pool -> f16. 256 blocks x 4 rows, 64 thr/row.
// ---------------------------------------------------------------------------
__global__ __launch_bounds__(256) void pool_kernel(
    const float* __restrict__ hidden, const int* __restrict__ sutt,
    const int* __restrict__ sstart, const int* __restrict__ send,
    _Float16* __restrict__ pooledh)
{
    const int bm = blockIdx.x * 4 + (threadIdx.x >> 6);
    const int lane = threadIdx.x & 63;
    const int b  = bm >> 8;
    const int u  = sutt[bm];
    const int st = sstart[bm];
    const int en = send[bm];
    const float inv = 1.0f / (float)(en - st);
    const float* src = hidden + ((size_t)(b * U_ + u) * L_) * H_ + lane * 12;
    float4 s[3];
    #pragma unroll
    for (int q = 0; q < 3; ++q) s[q] = make_float4(0.f, 0.f, 0.f, 0.f);
    for (int l = st; l < en; ++l) {
        const float* p = src + (size_t)l * H_;
        #pragma unroll
        for (int q = 0; q < 3; ++q) {
            float4 v = *(const float4*)(p + q * 4);
            s[q].x += v.x; s[q].y += v.y; s[q].z += v.z; s[q].w += v.w;
        }
    }
    _Float16* gp = pooledh + (size_t)bm * H_ + lane * 12;
    #pragma unroll
    for (int q = 0; q < 3; ++q) {
        half4t hv;
        hv[0] = (_Float16)(s[q].x * inv); hv[1] = (_Float16)(s[q].y * inv);
        hv[2] = (_Float16)(s[q].z * inv); hv[3] = (_Float16)(s[q].w * inv);
        *(half4t*)(gp + q * 4) = hv;
    }
}

// ---------------------------------------------------------------------------
// Kernel 2: hi/hj projection. 64 blocks x 16 rows, 16x16x32 MFMA vs W1abs.
// hiF[row][160] (b1 folded), hjT[160][1024] transposed.
// ---------------------------------------------------------------------------
__global__ __launch_bounds__(256) void hihj_kernel(
    const _Float16* __restrict__ pooledh, const float* __restrict__ b1,
    const _Float16* __restrict__ W1abs,
    float* __restrict__ hiF, float* __restrict__ hjT)
{
    __shared__ __align__(16) _Float16 spool[16 * 776];
    const int blk = blockIdx.x;
    const int tid = threadIdx.x;
    for (int e = tid; e < 16 * 96; e += 256) {
        int r = e / 96, c = e - r * 96;
        *(half8*)&spool[r * 776 + c * 8] =
            *(const half8*)&pooledh[(size_t)(blk * 16 + r) * H_ + c * 8];
    }
    __syncthreads();

    const int w = tid >> 6, lane = tid & 63;
    const int g = lane >> 4, l15 = lane & 15;
    floatx4 acc[5];
    #pragma unroll
    for (int u5 = 0; u5 < 5; ++u5) acc[u5] = (floatx4){0.f, 0.f, 0.f, 0.f};
    const _Float16* aB = &spool[l15 * 776 + g * 8];
    for (int kc = 0; kc < 24; ++kc) {
        half8 av = *(const half8*)(aB + kc * 32);
        #pragma unroll
        for (int u5 = 0; u5 < 5; ++u5) {
            const int u = w * 5 + u5;
            half8 bv = *(const half8*)(W1abs + (size_t)((kc * 20 + u) * 64 + lane) * 8);
            acc[u5] = __builtin_amdgcn_mfma_f32_16x16x32_f16(av, bv, acc[u5], 0, 0, 0);
        }
    }
    const int row0 = blk * 16 + g * 4;
    #pragma unroll
    for (int u5 = 0; u5 < 5; ++u5) {
        const int n = (w * 5 + u5) * 16 + l15;
        if (n < HID_) {
            float b1v = b1[n];
            #pragma unroll
            for (int r = 0; r < 4; ++r)
                hiF[(size_t)(row0 + r) * 160 + n] = acc[u5][r] + b1v;
        } else if (n >= 160 && n < 160 + HID_) {
            *(float4*)&hjT[(size_t)(n - 160) * 1024 + row0] =
                make_float4(acc[u5][0], acc[u5][1], acc[u5][2], acc[u5][3]);
        }
    }
}

// ---------------------------------------------------------------------------
// Kernel 3: fused pair MLP, transposed formulation (R5 structure) + 2-deep
// software pipeline. 1 wave/block, launch_bounds(64,1) -> full 512-reg budget
// (R6 lesson: 240 accumulators DO NOT fit 2 waves/SIMD; never request it).
// Wave owns 2 tiles (i0,i0+1) x 32 j. Stage1 A/W prefetched 2 chunks deep
// (~128 VGPR); stage2 2-deep. h1 bounce via 21.3 KB LDS (stride 170: 2-way
// bank alias only = free).
// C/D 32x32: col=lane&31, row=(reg&3)+8*(reg>>2)+4*(lane>>5).  [R4-verified]
// ---------------------------------------------------------------------------
__global__ __launch_bounds__(64, 1) void pair_mlp_kernel(
    const _Float16* __restrict__ pooledh,
    const float* __restrict__ hiF, const float* __restrict__ hjT,
    const _Float16* __restrict__ W1cs, const _Float16* __restrict__ W2s,
    const float2* __restrict__ bw, const float* __restrict__ b3,
    float* __restrict__ logits)
{
    __shared__ __align__(16) _Float16 h1L[2 * 32 * 170];   // 21760 B

    int q = blockIdx.x;
    const int b = q / 576;
    int r = q - b * 576;
    int jt = 0;
    while (r >= 128 - 16 * jt) { r -= 128 - 16 * jt; ++jt; }
    const int p = 16 * jt + r;           // i-pair: i in {2p, 2p+1}
    const int i0 = 2 * p, j0 = jt * 32;
    const int bm = b * M_;
    const int lane = threadIdx.x & 63;
    const int c31 = lane & 31;
    const int hw = lane >> 5;            // half-wave 0/1

    const _Float16* pjp  = pooledh + (size_t)(bm + j0 + c31) * H_ + (hw << 3);
    const _Float16* pip0 = pooledh + (size_t)(bm + i0) * H_ + (hw << 3);
    const _Float16* pip1 = pooledh + (size_t)(bm + i0 + 1) * H_ + (hw << 3);

    floatx16 acc1[2][5];
    #pragma unroll
    for (int t = 0; t < 2; ++t)
        #pragma unroll
        for (int t1 = 0; t1 < 5; ++t1)
            #pragma unroll
            for (int e = 0; e < 16; ++e) acc1[t][t1][e] = 0.f;

    // ---- stage-1 prefetch buffers: 2 chunks deep ----
    half8 Apj0[2], Apj1[2], Ai00[2], Ai01[2], Ai10[2], Ai11[2];
    half8 Wf[2][10];
    #pragma unroll
    for (int c = 0; c < 2; ++c) {
        const int kb = c * 32;
        Apj0[c] = *(const half8*)(pjp + kb);
        Apj1[c] = *(const half8*)(pjp + kb + 16);
        Ai00[c] = *(const half8*)(pip0 + kb);
        Ai01[c] = *(const half8*)(pip0 + kb + 16);
        Ai10[c] = *(const half8*)(pip1 + kb);
        Ai11[c] = *(const half8*)(pip1 + kb + 16);
        const _Float16* wb = W1cs + (size_t)c * 5120 + lane * 8;
        #pragma unroll
        for (int u = 0; u < 10; ++u) Wf[c][u] = *(const half8*)(wb + u * 512);
    }

    // ---- stage 1: K=768, 24 chunks of 32; consume cur, prefetch kc+2 ----
    for (int kc = 0; kc < 24; ++kc) {
        const int cur = kc & 1;
        half8 npj0, npj1, ni00, ni01, ni10, ni11, nW[10];
        if (kc < 22) {
            const int kb = (kc + 2) * 32;
            npj0 = *(const half8*)(pjp + kb);
            npj1 = *(const half8*)(pjp + kb + 16);
            ni00 = *(const half8*)(pip0 + kb);
            ni01 = *(const half8*)(pip0 + kb + 16);
            ni10 = *(const half8*)(pip1 + kb);
            ni11 = *(const half8*)(pip1 + kb + 16);
            const _Float16* wb = W1cs + (size_t)(kc + 2) * 5120 + lane * 8;
            #pragma unroll
            for (int u = 0; u < 10; ++u) nW[u] = *(const half8*)(wb + u * 512);
        }
        #pragma unroll
        for (int h = 0; h < 2; ++h) {
            half8 pj = h ? Apj1[cur] : Apj0[cur];
            half8 a0 = (h ? Ai01[cur] : Ai00[cur]) * pj;
            half8 a1 = (h ? Ai11[cur] : Ai10[cur]) * pj;
            #pragma unroll
            for (int t1 = 0; t1 < 5; ++t1) {
                half8 wf = Wf[cur][h * 5 + t1];
                acc1[0][t1] = __builtin_amdgcn_mfma_f32_32x32x16_f16(
                    wf, a0, acc1[0][t1], 0, 0, 0);
                acc1[1][t1] = __builtin_amdgcn_mfma_f32_32x32x16_f16(
                    wf, a1, acc1[1][t1], 0, 0, 0);
            }
        }
        if (kc < 22) {
            Apj0[cur] = npj0; Apj1[cur] = npj1;
            Ai00[cur] = ni00; Ai01[cur] = ni01;
            Ai10[cur] = ni10; Ai11[cur] = ni11;
            #pragma unroll
            for (int u = 0; u < 10; ++u) Wf[cur][u] = nW[u];
        }
    }

    // ---- epilogue 1: h1 = relu(acc + hiF + hjT) -> LDS (hj shared by tiles) --
    #pragma unroll
    for (int t1 = 0; t1 < 5; ++t1) {
        #pragma unroll
        for (int qd = 0; qd < 4; ++qd) {
            const int n1 = t1 * 32 + 8 * qd + 4 * hw;
            float hj0 = hjT[(size_t)(n1 + 0) * 1024 + bm + j0 + c31];
            float hj1 = hjT[(size_t)(n1 + 1) * 1024 + bm + j0 + c31];
            float hj2 = hjT[(size_t)(n1 + 2) * 1024 + bm + j0 + c31];
            float hj3 = hjT[(size_t)(n1 + 3) * 1024 + bm + j0 + c31];
            #pragma unroll
            for (int t = 0; t < 2; ++t) {
                float4 hiv = *(const float4*)&hiF[(size_t)(bm + i0 + t) * 160 + n1];
                half4t hv;
                hv[0] = (_Float16)fmaxf(acc1[t][t1][4 * qd + 0] + hiv.x + hj0, 0.f);
                hv[1] = (_Float16)fmaxf(acc1[t][t1][4 * qd + 1] + hiv.y + hj1, 0.f);
                hv[2] = (_Float16)fmaxf(acc1[t][t1][4 * qd + 2] + hiv.z + hj2, 0.f);
                hv[3] = (_Float16)fmaxf(acc1[t][t1][4 * qd + 3] + hiv.w + hj3, 0.f);
                *(half4t*)&h1L[(t * 32 + c31) * 170 + n1] = hv;
            }
        }
    }
    __syncthreads();   // single wave; forces LDS write->read ordering

    // ---- stage 2 + 3 per tile, 2-deep pipelined ----
    const float b3v = b3[0];
    #pragma unroll
    for (int t = 0; t < 2; ++t) {
        floatx16 acc2[5];
        #pragma unroll
        for (int t2 = 0; t2 < 5; ++t2)
            #pragma unroll
            for (int e = 0; e < 16; ++e) acc2[t2][e] = 0.f;

        half8 W2b[2][5], h1b[2];
        #pragma unroll
        for (int c = 0; c < 2; ++c) {
            const _Float16* wb = W2s + (size_t)(c * 5) * 512 + lane * 8;
            #pragma unroll
            for (int t2 = 0; t2 < 5; ++t2) W2b[c][t2] = *(const half8*)(wb + t2 * 512);
            h1b[c] = *(const half8*)&h1L[(t * 32 + c31) * 170 + c * 16 + hw * 8];
        }
        for (int kc2 = 0; kc2 < 10; ++kc2) {
            const int cur = kc2 & 1;
            half8 nw[5], nh;
            if (kc2 < 8) {
                const _Float16* wb = W2s + (size_t)((kc2 + 2) * 5) * 512 + lane * 8;
                #pragma unroll
                for (int t2 = 0; t2 < 5; ++t2) nw[t2] = *(const half8*)(wb + t2 * 512);
                nh = *(const half8*)&h1L[(t * 32 + c31) * 170 + (kc2 + 2) * 16 + hw * 8];
            }
            #pragma unroll
            for (int t2 = 0; t2 < 5; ++t2)
                acc2[t2] = __builtin_amdgcn_mfma_f32_32x32x16_f16(
                    W2b[cur][t2], h1b[cur], acc2[t2], 0, 0, 0);
            if (kc2 < 8) {
                #pragma unroll
                for (int t2 = 0; t2 < 5; ++t2) W2b[cur][t2] = nw[t2];
                h1b[cur] = nh;
            }
        }

        // stage 3
        float sown = 0.f;
        #pragma unroll
        for (int t2 = 0; t2 < 5; ++t2) {
            #pragma unroll
            for (int qd = 0; qd < 4; ++qd) {
                const int n2 = t2 * 32 + 8 * qd + 4 * hw;
                float4 bw01 = *(const float4*)&bw[n2];
                float4 bw23 = *(const float4*)&bw[n2 + 2];
                sown += fmaxf(acc2[t2][4 * qd + 0] + bw01.x, 0.f) * bw01.y;
                sown += fmaxf(acc2[t2][4 * qd + 1] + bw01.z, 0.f) * bw01.w;
                sown += fmaxf(acc2[t2][4 * qd + 2] + bw23.x, 0.f) * bw23.y;
                sown += fmaxf(acc2[t2][4 * qd + 3] + bw23.z, 0.f) * bw23.w;
            }
        }
        float s = sown + __shfl_xor(sown, 32);
        const int i = i0 + t;
        const int j = j0 + c31;
        if (lane < 32 && j < i)
            logits[(size_t)(bm + i) * M_ + j] = s + b3v;
    }
}

// ---------------------------------------------------------------------------
// Kernel 4: per-row softmax over j<=i, clipped label-mass NLL, atomic sum.
// ---------------------------------------------------------------------------
__global__ __launch_bounds__(256) void loss_kernel(
    const float* __restrict__ logits, const float* __restrict__ labels,
    float* __restrict__ out)
{
    const int bm = blockIdx.x;
    const int i  = bm & (M_ - 1);
    const int j  = threadIdx.x;
    __shared__ float red[4];
    __shared__ float bcast;

    float val = (j < i) ? logits[(size_t)bm * M_ + j]
                        : ((j == i) ? 0.0f : -1e30f);

    float m = val;
    #pragma unroll
    for (int off = 32; off >= 1; off >>= 1) m = fmaxf(m, __shfl_down(m, off, 64));
    const int wave = j >> 6, lane = j & 63;
    if (lane == 0) red[wave] = m;
    __syncthreads();
    if (j == 0) bcast = fmaxf(fmaxf(red[0], red[1]), fmaxf(red[2], red[3]));
    __syncthreads();
    const float mm = bcast;

    float e = (j <= i) ? expf(val - mm) : 0.0f;
    float s = e;
    #pragma unroll
    for (int off = 32; off >= 1; off >>= 1) s += __shfl_down(s, off, 64);
    __syncthreads();
    if (lane == 0) red[wave] = s;
    __syncthreads();
    if (j == 0) bcast = red[0] + red[1] + red[2] + red[3];
    __syncthreads();
    const float ssum = bcast;

    float prob = (j <= i) ? (e / ssum) : -1000.0f;
    float lab = labels[(size_t)bm * M_ + j];
    float tv = prob * lab;
    tv = fminf(fmaxf(tv, 1e-8f), 1.0f - 1e-8f);
    float rs = tv;
    #pragma unroll
    for (int off = 32; off >= 1; off >>= 1) rs += __shfl_down(rs, off, 64);
    __syncthreads();
    if (lane == 0) red[wave] = rs;
    __syncthreads();
    if (j == 0) atomicAdd(out, -logf(red[0] + red[1] + red[2] + red[3]));
}

// ---------------------------------------------------------------------------
extern "C" void kernel_launch(void* const* d_in, const int* in_sizes, int n_in,
                              void* d_out, int out_size, void* d_ws, size_t ws_size,
                              hipStream_t stream)
{
    const float* hidden = (const float*)d_in[0];
    const int*   sutt   = (const int*)d_in[1];
    const int*   sstart = (const int*)d_in[2];
    const int*   send   = (const int*)d_in[3];
    const float* labels = (const float*)d_in[4];
    const float* W1     = (const float*)d_in[5];
    const float* b1     = (const float*)d_in[6];
    const float* W2     = (const float*)d_in[7];
    const float* b2     = (const float*)d_in[8];
    const float* W3     = (const float*)d_in[9];
    const float* b3     = (const float*)d_in[10];

    float* ws = (float*)d_ws;
    float*    hiF     = ws;                          // [1024][160]
    float*    hjT     = ws + 163840;                 // [160][1024]
    float*    logits  = ws + 327680;                 // 262144
    float2*   bw      = (float2*)(ws + 589824);      // 160 float2
    _Float16* pooledh = (_Float16*)(ws + 590144);    // 786432 f16
    _Float16* W1cs    = (_Float16*)(ws + 983360);    // 122880 f16
    _Float16* W2s     = (_Float16*)(ws + 1106240);   // 25600 f16
    _Float16* W1abs   = (_Float16*)(ws + 1119040);   // 245760 f16
    float* out = (float*)d_out;

    hipMemsetAsync(d_out, 0, sizeof(float), stream);

    prep_kernel<<<dim3(1540), 256, 0, stream>>>(W1, W2, b2, W3,
                                                W1cs, W2s, W1abs, bw);
    pool_kernel<<<dim3(256), 256, 0, stream>>>(hidden, sutt, sstart, send, pooledh);
    hihj_kernel<<<dim3(64), 256, 0, stream>>>(pooledh, b1, W1abs, hiF, hjT);
    pair_mlp_kernel<<<dim3(576 * B_), 64, 0, stream>>>(pooledh, hiF, hjT,
                                                       W1cs, W2s, bw, b3, logits);
    loss_kernel<<<dim3(B_ * M_), 256, 0, stream>>>(logits, labels, out);
}